// Round 1
// baseline (447.270 us; speedup 1.0000x reference)
//
#include <hip/hip_runtime.h>

#define B_  16
#define CIN 512
#define C_  64
#define H_  64
#define W_  160
#define HW  (H_*W_)   // 10240
#define NCH 32        // relation hw-chunks per batch

// ---------------- K1: transpose hm_w [64][512] -> wT [512][64] ----------------
__global__ __launch_bounds__(256) void k_transpose_w(const float* __restrict__ w,
                                                     float* __restrict__ wT) {
    int idx = blockIdx.x * 256 + threadIdx.x;      // idx = o*512 + i
    int o = idx >> 9, i = idx & 511;
    wT[i * C_ + o] = w[idx];
}

// ---------------- K2: unnorm[b][o][hw] = sum_i fcn[b][i][hw] * wT[i][o] -------
__global__ __launch_bounds__(256) void k_gemm1(const float* __restrict__ fcn,
                                               const float* __restrict__ wT,
                                               float* __restrict__ out) {
    const int hw = blockIdx.x * 256 + threadIdx.x;
    const int b  = blockIdx.y;
    const float* __restrict__ xp = fcn + (size_t)b * CIN * HW + hw;
    float acc[C_];
#pragma unroll
    for (int o = 0; o < C_; ++o) acc[o] = 0.f;
    for (int i = 0; i < CIN; ++i) {
        float x = xp[(size_t)i * HW];
        const float4* __restrict__ wr = reinterpret_cast<const float4*>(wT + i * C_);
#pragma unroll
        for (int o4 = 0; o4 < C_ / 4; ++o4) {
            float4 wv = wr[o4];
            acc[o4*4+0] = fmaf(x, wv.x, acc[o4*4+0]);
            acc[o4*4+1] = fmaf(x, wv.y, acc[o4*4+1]);
            acc[o4*4+2] = fmaf(x, wv.z, acc[o4*4+2]);
            acc[o4*4+3] = fmaf(x, wv.w, acc[o4*4+3]);
        }
    }
    float* __restrict__ op = out + (size_t)b * C_ * HW + hw;
#pragma unroll
    for (int o = 0; o < C_; ++o) op[(size_t)o * HW] = acc[o];
}

// ---------------- K3/K8: row softmax over HW + dsnt coords --------------------
// pout may alias in (elementwise in-place), so no __restrict__ on those two.
__global__ __launch_bounds__(256) void k_softmax_dsnt(const float* in,
                                                      float* pout,
                                                      float* __restrict__ coords) {
    const int row = blockIdx.x;                  // b*64 + c
    const int tid = threadIdx.x;
    const float4* in4  = reinterpret_cast<const float4*>(in + (size_t)row * HW);
    float4*       out4 = reinterpret_cast<float4*>(pout + (size_t)row * HW);
    __shared__ float red[16];

    float m = -3.402823466e38f;
    for (int j = tid; j < HW/4; j += 256) {
        float4 u = in4[j];
        m = fmaxf(m, fmaxf(fmaxf(u.x, u.y), fmaxf(u.z, u.w)));
    }
#pragma unroll
    for (int off = 32; off > 0; off >>= 1) m = fmaxf(m, __shfl_xor(m, off));
    if ((tid & 63) == 0) red[tid >> 6] = m;
    __syncthreads();
    m = fmaxf(fmaxf(red[0], red[1]), fmaxf(red[2], red[3]));

    const float invw = 1.f / W_, invh = 1.f / H_;
    float s = 0.f, sx = 0.f, sy = 0.f;
    for (int j = tid; j < HW/4; j += 256) {
        float4 u = in4[j];
        int e0 = j * 4;
        int h  = e0 / W_;
        int w0 = e0 - h * W_;
        float y  = (2*h + 1) * invh - 1.f;
        float x0 = (2*w0 + 1) * invw - 1.f;
        float e;
        e = __expf(u.x - m); s += e; sy = fmaf(e, y, sy); sx = fmaf(e, x0,          sx);
        e = __expf(u.y - m); s += e; sy = fmaf(e, y, sy); sx = fmaf(e, x0 + 2*invw, sx);
        e = __expf(u.z - m); s += e; sy = fmaf(e, y, sy); sx = fmaf(e, x0 + 4*invw, sx);
        e = __expf(u.w - m); s += e; sy = fmaf(e, y, sy); sx = fmaf(e, x0 + 6*invw, sx);
    }
#pragma unroll
    for (int off = 32; off > 0; off >>= 1) {
        s  += __shfl_xor(s,  off);
        sx += __shfl_xor(sx, off);
        sy += __shfl_xor(sy, off);
    }
    if ((tid & 63) == 0) { int w = tid >> 6; red[4+w] = s; red[8+w] = sx; red[12+w] = sy; }
    __syncthreads();
    s  = red[4] + red[5] + red[6]  + red[7];
    sx = red[8] + red[9] + red[10] + red[11];
    sy = red[12] + red[13] + red[14] + red[15];
    float inv = 1.f / s;

    for (int j = tid; j < HW/4; j += 256) {
        float4 u = in4[j];
        float4 p;
        p.x = __expf(u.x - m) * inv;
        p.y = __expf(u.y - m) * inv;
        p.z = __expf(u.z - m) * inv;
        p.w = __expf(u.w - m) * inv;
        out4[j] = p;
    }
    if (tid == 0) {
        coords[row*2 + 0] = sx * inv;
        coords[row*2 + 1] = sy * inv;
    }
}

// ---------------- K4: depthwise 5x5 SAME conv ---------------------------------
__global__ __launch_bounds__(256) void k_dwconv(const float* __restrict__ in,
                                                const float* __restrict__ wt,
                                                float* __restrict__ out) {
    const int bc = blockIdx.z;
    const int c  = bc & (C_ - 1);
    const int w0 = blockIdx.x * 32, h0 = blockIdx.y * 16;
    __shared__ float tile[20][36];
    const float* __restrict__ ip = in + (size_t)bc * HW;
    for (int idx = threadIdx.x; idx < 20*36; idx += 256) {
        int r  = idx / 36, cc = idx - r * 36;
        int gy = h0 + r - 2, gx = w0 + cc - 2;
        float v = 0.f;
        if (gy >= 0 && gy < H_ && gx >= 0 && gx < W_) v = ip[gy * W_ + gx];
        tile[r][cc] = v;
    }
    float wv[25];
#pragma unroll
    for (int k = 0; k < 25; ++k) wv[k] = wt[c * 25 + k];
    __syncthreads();
    const int tx = threadIdx.x & 31, ty = threadIdx.x >> 5;
    float* __restrict__ op = out + (size_t)bc * HW;
#pragma unroll
    for (int yy = 0; yy < 2; ++yy) {
        const int ly = ty + yy * 8;
        float acc = 0.f;
#pragma unroll
        for (int dy = 0; dy < 5; ++dy)
#pragma unroll
            for (int dx = 0; dx < 5; ++dx)
                acc = fmaf(tile[ly + dy][tx + dx], wv[dy*5 + dx], acc);
        op[(size_t)(h0 + ly) * W_ + w0 + tx] = acc;
    }
}

// ---------------- K5: relation partial sums A·A^T over hw chunk ---------------
__global__ __launch_bounds__(256) void k_rel_partial(const float* __restrict__ A,
                                                     float* __restrict__ part) {
    const int b = blockIdx.y, ch = blockIdx.x;
    const int hw0 = ch * (HW / NCH);             // 320 per chunk
    __shared__ float a[64 * 68];                 // [hw_local][c], pad 68 (16B aligned)
    float acc[4][4];
#pragma unroll
    for (int i = 0; i < 4; ++i)
#pragma unroll
        for (int j = 0; j < 4; ++j) acc[i][j] = 0.f;
    const int c0 = (threadIdx.x & 15) * 4, d0 = (threadIdx.x >> 4) * 4;
    for (int hb = 0; hb < HW / NCH; hb += 64) {
        __syncthreads();
        for (int e = threadIdx.x; e < 4096; e += 256) {
            int cc = e >> 6, hl = e & 63;
            a[hl * 68 + cc] = A[(size_t)(b * C_ + cc) * HW + hw0 + hb + hl];
        }
        __syncthreads();
#pragma unroll 2
        for (int hl = 0; hl < 64; ++hl) {
            float4 va = *reinterpret_cast<const float4*>(&a[hl * 68 + c0]);
            float4 vb = *reinterpret_cast<const float4*>(&a[hl * 68 + d0]);
            acc[0][0]=fmaf(va.x,vb.x,acc[0][0]); acc[0][1]=fmaf(va.x,vb.y,acc[0][1]);
            acc[0][2]=fmaf(va.x,vb.z,acc[0][2]); acc[0][3]=fmaf(va.x,vb.w,acc[0][3]);
            acc[1][0]=fmaf(va.y,vb.x,acc[1][0]); acc[1][1]=fmaf(va.y,vb.y,acc[1][1]);
            acc[1][2]=fmaf(va.y,vb.z,acc[1][2]); acc[1][3]=fmaf(va.y,vb.w,acc[1][3]);
            acc[2][0]=fmaf(va.z,vb.x,acc[2][0]); acc[2][1]=fmaf(va.z,vb.y,acc[2][1]);
            acc[2][2]=fmaf(va.z,vb.z,acc[2][2]); acc[2][3]=fmaf(va.z,vb.w,acc[2][3]);
            acc[3][0]=fmaf(va.w,vb.x,acc[3][0]); acc[3][1]=fmaf(va.w,vb.y,acc[3][1]);
            acc[3][2]=fmaf(va.w,vb.z,acc[3][2]); acc[3][3]=fmaf(va.w,vb.w,acc[3][3]);
        }
    }
    float* __restrict__ pp = part + (size_t)(b * NCH + ch) * 4096;
#pragma unroll
    for (int i = 0; i < 4; ++i)
#pragma unroll
        for (int j = 0; j < 4; ++j)
            pp[(c0 + i) * 64 + d0 + j] = acc[i][j];
}

// ---------------- K6: reduce partials, rowmax-sub softmax, write R^T ----------
__global__ __launch_bounds__(256) void k_rel_finalize(const float* __restrict__ part,
                                                      float* __restrict__ RT) {
    const int b = blockIdx.x;
    __shared__ float rel[64][65];
    for (int e = threadIdx.x; e < 4096; e += 256) {
        float s = 0.f;
        for (int k = 0; k < NCH; ++k) s += part[(size_t)(b * NCH + k) * 4096 + e];
        rel[e >> 6][e & 63] = s;
    }
    __syncthreads();
    if (threadIdx.x < 64) {
        int cc = threadIdx.x;
        // softmax(rowmax - r) == exp(rowmin - r) / sum(exp(rowmin - r))
        float mn = rel[cc][0];
        for (int d = 1; d < 64; ++d) mn = fminf(mn, rel[cc][d]);
        float s = 0.f;
        for (int d = 0; d < 64; ++d) s += __expf(mn - rel[cc][d]);
        float inv = 1.f / s;
        for (int d = 0; d < 64; ++d)
            RT[b * 4096 + d * 64 + cc] = __expf(mn - rel[cc][d]) * inv;
    }
}

// ---------------- K7: feat_e = R·A ; t = (feat_e + A) * fu --------------------
__global__ __launch_bounds__(256) void k_feate(const float* __restrict__ A,
                                               const float* __restrict__ RT,
                                               const float* __restrict__ fu,
                                               float* __restrict__ tout) {
    const int hw = blockIdx.x * 256 + threadIdx.x;
    const int b  = blockIdx.y;
    const float* __restrict__ ap = A + (size_t)b * C_ * HW + hw;
    float acc[C_];
#pragma unroll
    for (int o = 0; o < C_; ++o) acc[o] = 0.f;
    for (int d = 0; d < C_; ++d) {
        float x = ap[(size_t)d * HW];
        const float4* __restrict__ rr = reinterpret_cast<const float4*>(RT + b * 4096 + d * 64);
#pragma unroll
        for (int o4 = 0; o4 < C_ / 4; ++o4) {
            float4 rv = rr[o4];
            acc[o4*4+0] = fmaf(x, rv.x, acc[o4*4+0]);
            acc[o4*4+1] = fmaf(x, rv.y, acc[o4*4+1]);
            acc[o4*4+2] = fmaf(x, rv.z, acc[o4*4+2]);
            acc[o4*4+3] = fmaf(x, rv.w, acc[o4*4+3]);
        }
    }
    float* __restrict__ op = tout + (size_t)b * C_ * HW + hw;
#pragma unroll
    for (int cc = 0; cc < C_; ++cc) {
        float t = (acc[cc] + ap[(size_t)cc * HW]) * fu[cc];
        op[(size_t)cc * HW] = t;
    }
}

// ------------------------------------------------------------------------------
extern "C" void kernel_launch(void* const* d_in, const int* in_sizes, int n_in,
                              void* d_out, int out_size, void* d_ws, size_t ws_size,
                              hipStream_t stream) {
    const float* fcn = (const float*)d_in[0];
    const float* hmw = (const float*)d_in[1];
    const float* dww = (const float*)d_in[2];
    const float* fuw = (const float*)d_in[3];
    float* out = (float*)d_out;
    char* ws = (char*)d_ws;

    float* wT   = (float*)(ws);                                    // 512*64*4   = 128 KB
    float* buf1 = (float*)(ws + 131072);                           // 42 MB (unnorm -> p -> t)
    float* part = (float*)(ws + 131072 + 41943040);                // 16*32*4096*4 = 8.4 MB
    float* RT   = (float*)(ws + 131072 + 41943040 + 8388608);      // 16*4096*4 = 256 KB

    float* hm2            = out + 4096;   // heatmap output region doubles as A buffer
    float* final_coords   = out;
    float* interme_coords = out + 2048;

    hipLaunchKernelGGL(k_transpose_w,  dim3(128),       dim3(256), 0, stream, hmw, wT);
    hipLaunchKernelGGL(k_gemm1,        dim3(40, 16),    dim3(256), 0, stream, fcn, wT, buf1);
    hipLaunchKernelGGL(k_softmax_dsnt, dim3(1024),      dim3(256), 0, stream, buf1, buf1, interme_coords);
    hipLaunchKernelGGL(k_dwconv,       dim3(5, 4, 1024),dim3(256), 0, stream, buf1, dww, hm2);
    hipLaunchKernelGGL(k_rel_partial,  dim3(NCH, 16),   dim3(256), 0, stream, hm2, part);
    hipLaunchKernelGGL(k_rel_finalize, dim3(16),        dim3(256), 0, stream, part, RT);
    hipLaunchKernelGGL(k_feate,        dim3(40, 16),    dim3(256), 0, stream, hm2, RT, fuw, buf1);
    hipLaunchKernelGGL(k_softmax_dsnt, dim3(1024),      dim3(256), 0, stream, buf1, hm2, final_coords);
}